// Round 8
// baseline (157.610 us; speedup 1.0000x reference)
//
#include <hip/hip_runtime.h>

#define BIGV 1e10f
#define EHUGE (-(1 << 28))

constexpr float INV_LN2 = 1.4426950408889634f;
constexpr float LN2f    = 0.6931471805599453f;

// ---------------- Phase 1: ND[b][j][i] = -(|x_i - y_j|^2)/ln2 as f16 ----------------
__global__ __launch_bounds__(256) void dist_kernel(
    const float* __restrict__ X, const float* __restrict__ Y,
    _Float16* __restrict__ ND)
{
  const int b  = blockIdx.x;
  const int j0 = blockIdx.y * 8;
  const int t  = threadIdx.x;

  __shared__ float4 ysh4[8][4];
  __shared__ float  y2sh[8];
  float* yshf = (float*)ysh4;

  const float* xb = X + (size_t)b * 512 * 16;
  const float* yb = Y + (size_t)b * 512 * 16;

  if (t < 128) yshf[t] = yb[(size_t)(j0 + (t >> 4)) * 16 + (t & 15)];
  __syncthreads();
  if (t < 8) {
    float s = 0.f;
    #pragma unroll
    for (int q = 0; q < 16; ++q) s = fmaf(yshf[t * 16 + q], yshf[t * 16 + q], s);
    y2sh[t] = s;
  }
  __syncthreads();

  float xa[16], xc[16];
  float x2a = 0.f, x2c = 0.f;
  {
    const float4* pa = (const float4*)(xb + (size_t)(2 * t) * 16);
    float4 A0 = pa[0], A1 = pa[1], A2 = pa[2], A3 = pa[3];
    float4 B0 = pa[4], B1 = pa[5], B2 = pa[6], B3 = pa[7];
    float ta[16] = { A0.x,A0.y,A0.z,A0.w, A1.x,A1.y,A1.z,A1.w,
                     A2.x,A2.y,A2.z,A2.w, A3.x,A3.y,A3.z,A3.w };
    float tb[16] = { B0.x,B0.y,B0.z,B0.w, B1.x,B1.y,B1.z,B1.w,
                     B2.x,B2.y,B2.z,B2.w, B3.x,B3.y,B3.z,B3.w };
    #pragma unroll
    for (int q = 0; q < 16; ++q) {
      xa[q] = ta[q]; x2a = fmaf(ta[q], ta[q], x2a);
      xc[q] = tb[q]; x2c = fmaf(tb[q], tb[q], x2c);
    }
  }

  unsigned int* outp = (unsigned int*)(ND + ((size_t)b * 512 + j0) * 512);
  #pragma unroll
  for (int jj = 0; jj < 8; ++jj) {
    float4 y0 = ysh4[jj][0], y1 = ysh4[jj][1], y2v = ysh4[jj][2], y3 = ysh4[jj][3];
    float yv[16] = { y0.x,y0.y,y0.z,y0.w, y1.x,y1.y,y1.z,y1.w,
                     y2v.x,y2v.y,y2v.z,y2v.w, y3.x,y3.y,y3.z,y3.w };
    float da = 0.f, dc = 0.f;
    #pragma unroll
    for (int q = 0; q < 16; ++q) {
      da = fmaf(xa[q], yv[q], da);
      dc = fmaf(xc[q], yv[q], dc);
    }
    const float nda = (2.f * da - x2a - y2sh[jj]) * INV_LN2;
    const float ndc = (2.f * dc - x2c - y2sh[jj]) * INV_LN2;
    const unsigned short lo = __builtin_bit_cast(unsigned short, (_Float16)nda);
    const unsigned short hi = __builtin_bit_cast(unsigned short, (_Float16)ndc);
    outp[(size_t)jj * 256 + t] = ((unsigned int)hi << 16) | lo;
  }
}

// ---------------- Phase 2: (mantissa, exponent)-domain wavefront DP ----------------
// V(i,j) = 2^{-r'} stored as q*2^E, q in [0.5,1), E int. Recurrence:
// V = 2^{nd} * (Vdg + Vup + Vleft): E* = max3(E); ldexp each q to E*; sum;
// mul by e = exp2(max(nd,-100)) (off-chain, from f16 table); renorm via
// exponent-bit extract + ldexp. NO transcendentals on the serial chain.
// Same 4-wave lag-5-phase schedule as round 7 (verified): wave w rows
// 128w+1..128w+128, lane l rows a+1,a+2 (a=128w+2l), col j=t-l; DPP wf_sr1
// cross-lane; ring (q,E) in LDS cross-wave.
template<bool PRE>
__global__ __launch_bounds__(256, 1) void dp_kernel(
    const _Float16* __restrict__ ND, const float* __restrict__ X,
    const float* __restrict__ Y, float* __restrict__ out)
{
  const int b   = blockIdx.x;
  const int tid = threadIdx.x;
  const int w   = tid >> 6;
  const int l   = tid & 63;
  const int a   = 128 * w + 2 * l;

  __shared__ float ring_q[3][64];
  __shared__ int   ring_E[3][64];

  const _Float16* nb    = ND + (size_t)b * 512 * 512;
  const float*    ybase = Y + (size_t)b * 512 * 16;

  // DP state: rows a+1 (P0), a+2 (P1) at col j-1
  float P0q = 0.f, P1q = 0.f;
  int   P0E = EHUGE, P1E = EHUGE;
  float dgq = (w == 0 && l == 0) ? 1.0f : 0.f;    // s(0,0)=1 for the corner
  int   dgE = (w == 0 && l == 0) ? 0 : EHUGE;
  float lastq = 0.f;
  int   lastE = EHUGE;

  unsigned ds0 = 0, ds1 = 0, ds2 = 0, ds3 = 0;
  float xr0[16], xr1[16];
  float x20 = 0.f, x21 = 0.f;

  if constexpr (PRE) {
    #pragma unroll
    for (int s = 0; s < 4; ++s) {
      int jc = s - l; jc = jc < 0 ? 0 : jc;
      unsigned v = *(const unsigned*)(nb + ((size_t)jc << 9) + a);
      if (s == 0) ds0 = v; else if (s == 1) ds1 = v;
      else if (s == 2) ds2 = v; else ds3 = v;
    }
  } else {
    const float4* px = (const float4*)(X + ((size_t)b * 512 + a) * 16);
    float4 u0 = px[0], u1 = px[1], u2 = px[2], u3 = px[3];
    float4 u4 = px[4], u5 = px[5], u6 = px[6], u7 = px[7];
    float ta[16] = { u0.x,u0.y,u0.z,u0.w, u1.x,u1.y,u1.z,u1.w,
                     u2.x,u2.y,u2.z,u2.w, u3.x,u3.y,u3.z,u3.w };
    float tb[16] = { u4.x,u4.y,u4.z,u4.w, u5.x,u5.y,u5.z,u5.w,
                     u6.x,u6.y,u6.z,u6.w, u7.x,u7.y,u7.z,u7.w };
    #pragma unroll
    for (int q = 0; q < 16; ++q) {
      xr0[q] = ta[q]; x20 = fmaf(ta[q], ta[q], x20);
      xr1[q] = tb[q]; x21 = fmaf(tb[q], tb[q], x21);
    }
  }
  __syncthreads();

#define SDTW_STEP(DSLOT, RQ, RE)                                               \
  {                                                                            \
    const int j = t - l;                                                       \
    float nd0, nd1;                                                            \
    if constexpr (PRE) {                                                       \
      const unsigned dw = DSLOT;                                               \
      int jn = t + 3 - l; jn = jn < 0 ? 0 : (jn > 511 ? 511 : jn);             \
      DSLOT = *(const unsigned*)(nb + ((size_t)jn << 9) + a);                  \
      nd0 = (float)__builtin_bit_cast(_Float16, (unsigned short)(dw & 0xffffu)); \
      nd1 = (float)__builtin_bit_cast(_Float16, (unsigned short)(dw >> 16));   \
    } else {                                                                   \
      int jc = j - 1; jc = jc < 0 ? 0 : (jc > 511 ? 511 : jc);                 \
      const float4* py = (const float4*)(ybase + (size_t)jc * 16);             \
      float4 v0 = py[0], v1 = py[1], v2 = py[2], v3 = py[3];                   \
      float yv[16] = { v0.x,v0.y,v0.z,v0.w, v1.x,v1.y,v1.z,v1.w,               \
                       v2.x,v2.y,v2.z,v2.w, v3.x,v3.y,v3.z,v3.w };             \
      float y2 = 0.f, d0 = 0.f, d1 = 0.f;                                      \
      _Pragma("unroll")                                                        \
      for (int q = 0; q < 16; ++q) {                                           \
        y2 = fmaf(yv[q], yv[q], y2);                                           \
        d0 = fmaf(xr0[q], yv[q], d0);                                          \
        d1 = fmaf(xr1[q], yv[q], d1);                                          \
      }                                                                        \
      nd0 = (2.f * d0 - x20 - y2) * INV_LN2;                                   \
      nd1 = (2.f * d1 - x21 - y2) * INV_LN2;                                   \
    }                                                                          \
    const float e0 = __builtin_amdgcn_exp2f(fmaxf(nd0, -100.f));               \
    const float e1 = __builtin_amdgcn_exp2f(fmaxf(nd1, -100.f));               \
    /* up = wave-shift-up-1 of (P1q,P1E); lane0 <- ring / corner-BIG */        \
    const int sq = __builtin_amdgcn_update_dpp(                                \
        __builtin_bit_cast(int, P1q), __builtin_bit_cast(int, P1q),            \
        0x138, 0xF, 0xF, false);                                               \
    const int sE = __builtin_amdgcn_update_dpp(P1E, P1E, 0x138, 0xF, 0xF, false); \
    float upq = __builtin_bit_cast(float, sq);                                 \
    int   upE = sE;                                                            \
    if (l == 0) { upq = (w == 0) ? 0.f : (RQ); upE = (w == 0) ? EHUGE : (RE); } \
    /* cell0 (row a+1, col j): dg, up, left=P0 */                              \
    const int Em0 = max(max(dgE, upE), P0E);                                   \
    const float t0a = ldexpf(dgq, dgE - Em0);                                  \
    const float t0b = ldexpf(upq, upE - Em0);                                  \
    const float t0c = ldexpf(P0q, P0E - Em0);                                  \
    const float n0  = e0 * ((t0a + t0b) + t0c);                                \
    const int  x0   = (int)(__builtin_bit_cast(unsigned, n0) >> 23) - 126;     \
    const float q0n = ldexpf(n0, -x0);                                         \
    const int   E0n = Em0 + x0;                                                \
    /* cell1 (row a+2, col j): dg=P0old, left=P1old, up=cell0 */               \
    const int Em1 = max(max(P0E, P1E), E0n);                                   \
    const float t1a = ldexpf(P0q, P0E - Em1);                                  \
    const float t1b = ldexpf(P1q, P1E - Em1);                                  \
    const float t1c = ldexpf(q0n, E0n - Em1);                                  \
    const float n1  = e1 * ((t1a + t1b) + t1c);                                \
    const int  x1   = (int)(__builtin_bit_cast(unsigned, n1) >> 23) - 126;     \
    const float q1n = ldexpf(n1, -x1);                                         \
    const int   E1n = Em1 + x1;                                                \
    const bool valid = (unsigned)(j - 1) < 512u;                               \
    const float q0f = valid ? q0n : 0.f;                                       \
    const int   E0f = valid ? E0n : EHUGE;                                     \
    const float q1f = valid ? q1n : 0.f;                                       \
    const int   E1f = valid ? E1n : EHUGE;                                     \
    lastq = valid ? q1n : lastq;                                               \
    lastE = valid ? E1n : lastE;                                               \
    if (l == 63 && w < 3 && valid) {                                           \
      ring_q[w][(j - 1) & 63] = q1f;                                           \
      ring_E[w][(j - 1) & 63] = E1f;                                           \
    }                                                                          \
    dgq = upq; dgE = upE;                                                      \
    P0q = q0f; P0E = E0f; P1q = q1f; P1E = E1f;                                \
  }

  for (int p = 0; p < 51; ++p) {
    const int pw = p - 5 * w;
    if (pw >= 0 && pw < 36) {
      const int tbase = 16 * pw + 1;
      const int wi = (w > 0) ? w - 1 : 0;
      const float4* rpq = (const float4*)(&ring_q[wi][0]);
      const int4*   rpe = (const int4*)(&ring_E[wi][0]);
      const int rb = ((tbase - 1) & 63) >> 2;     // {0,4,8,12}
      float4 gq0 = rpq[rb], gq1 = rpq[rb + 1], gq2 = rpq[rb + 2], gq3 = rpq[rb + 3];
      int4   ge0 = rpe[rb], ge1 = rpe[rb + 1], ge2 = rpe[rb + 2], ge3 = rpe[rb + 3];
      { const int t = tbase + 0;  SDTW_STEP(ds0, gq0.x, ge0.x) }
      { const int t = tbase + 1;  SDTW_STEP(ds1, gq0.y, ge0.y) }
      { const int t = tbase + 2;  SDTW_STEP(ds2, gq0.z, ge0.z) }
      { const int t = tbase + 3;  SDTW_STEP(ds3, gq0.w, ge0.w) }
      { const int t = tbase + 4;  SDTW_STEP(ds0, gq1.x, ge1.x) }
      { const int t = tbase + 5;  SDTW_STEP(ds1, gq1.y, ge1.y) }
      { const int t = tbase + 6;  SDTW_STEP(ds2, gq1.z, ge1.z) }
      { const int t = tbase + 7;  SDTW_STEP(ds3, gq1.w, ge1.w) }
      { const int t = tbase + 8;  SDTW_STEP(ds0, gq2.x, ge2.x) }
      { const int t = tbase + 9;  SDTW_STEP(ds1, gq2.y, ge2.y) }
      { const int t = tbase + 10; SDTW_STEP(ds2, gq2.z, ge2.z) }
      { const int t = tbase + 11; SDTW_STEP(ds3, gq2.w, ge2.w) }
      { const int t = tbase + 12; SDTW_STEP(ds0, gq3.x, ge3.x) }
      { const int t = tbase + 13; SDTW_STEP(ds1, gq3.y, ge3.y) }
      { const int t = tbase + 14; SDTW_STEP(ds2, gq3.z, ge3.z) }
      { const int t = tbase + 15; SDTW_STEP(ds3, gq3.w, ge3.w) }
    }
    __syncthreads();
  }
#undef SDTW_STEP

  // V(512,512) = lastq * 2^lastE ; r = -ln2*(log2(q)+E)
  if (tid == 255)
    out[b] = -LN2f * (__builtin_amdgcn_logf(lastq) + (float)lastE);
}

extern "C" void kernel_launch(void* const* d_in, const int* in_sizes, int n_in,
                              void* d_out, int out_size, void* d_ws, size_t ws_size,
                              hipStream_t stream)
{
  const float* x = (const float*)d_in[0];
  const float* y = (const float*)d_in[1];
  float* o = (float*)d_out;
  const size_t need = (size_t)64 * 512 * 512 * 2;
  if (ws_size >= need) {
    _Float16* nd = (_Float16*)d_ws;
    dist_kernel<<<dim3(64, 64), 256, 0, stream>>>(x, y, nd);
    dp_kernel<true><<<64, 256, 0, stream>>>(nd, x, y, o);
  } else {
    dp_kernel<false><<<64, 256, 0, stream>>>(nullptr, x, y, o);
  }
}

// Round 9
// 144.493 us; speedup vs baseline: 1.0908x; 1.0908x over previous
//
#include <hip/hip_runtime.h>

#define EHUGE (-(1 << 28))

constexpr float INV_LN2 = 1.4426950408889634f;
constexpr float LN2f    = 0.6931471805599453f;

// ---------------- Phase 1: ND2[b][p][j] ----------------
// p = row-pair (x rows 2p, 2p+1), packed as dword (lo = row 2p, hi = row 2p+1)
// of f16 nd = -|x_i - y_j|^2 / ln2. Row p stored at dword offset
// p*516 + (p&3) (+j): the (p&3) shift makes the DP lane's 4-step groups
// 16B-aligned. 516-dword stride keeps rows 16B-aligned.
__global__ __launch_bounds__(256) void dist2_kernel(
    const float* __restrict__ X, const float* __restrict__ Y,
    unsigned* __restrict__ ND2)
{
  const int b  = blockIdx.x;
  const int by = blockIdx.y;            // 4 pairs per block
  const int t  = threadIdx.x;

  __shared__ float ysh[512][17];        // +1 pad: conflict-free column reads
  __shared__ float y2sh[512];
  __shared__ float xsh[8][16];
  __shared__ float x2sh[8];

  const float* yb = Y + (size_t)b * 8192;
  const float* xb = X + (size_t)b * 8192 + (size_t)(8 * by) * 16;

  for (int idx = t; idx < 8192; idx += 256) ysh[idx >> 4][idx & 15] = yb[idx];
  if (t < 128) xsh[t >> 4][t & 15] = xb[t];
  __syncthreads();
  for (int r = t; r < 512; r += 256) {
    float s = 0.f;
    #pragma unroll
    for (int q = 0; q < 16; ++q) s = fmaf(ysh[r][q], ysh[r][q], s);
    y2sh[r] = s;
  }
  if (t < 8) {
    float s = 0.f;
    #pragma unroll
    for (int q = 0; q < 16; ++q) s = fmaf(xsh[t][q], xsh[t][q], s);
    x2sh[t] = s;
  }
  __syncthreads();

  const int pl = t >> 6;                // 0..3 (wave-uniform)
  const int jl = t & 63;
  const int p  = 4 * by + pl;           // p & 3 == pl

  float xa[16], xc[16];
  #pragma unroll
  for (int q = 0; q < 16; ++q) { xa[q] = xsh[2*pl][q]; xc[q] = xsh[2*pl+1][q]; }
  const float x2a = x2sh[2*pl], x2c = x2sh[2*pl+1];

  unsigned* outp = ND2 + (size_t)b * 132096 + (size_t)p * 516 + pl;
  #pragma unroll
  for (int jj = 0; jj < 8; ++jj) {
    const int j = jl + 64 * jj;
    float da = 0.f, dc = 0.f;
    #pragma unroll
    for (int q = 0; q < 16; ++q) {
      da = fmaf(xa[q], ysh[j][q], da);
      dc = fmaf(xc[q], ysh[j][q], dc);
    }
    const float nda = (2.f * da - x2a - y2sh[j]) * INV_LN2;
    const float ndc = (2.f * dc - x2c - y2sh[j]) * INV_LN2;
    const unsigned short lo = __builtin_bit_cast(unsigned short, (_Float16)nda);
    const unsigned short hi = __builtin_bit_cast(unsigned short, (_Float16)ndc);
    outp[j] = ((unsigned)hi << 16) | lo;
  }
}

// ---------------- Phase 2: (q, E)-domain wavefront DP ----------------
// V = q*2^E (exact power-of-2 scaling; exp folded via ndI/ndF split, no clamp).
// Schedule (verified r5-r8): wave w rows 128w+1..128w+128, lane l rows
// 2p+1,2p+2 (p = 64w+l), col j = t-l; DPP wf_sr1 cross-lane; LDS ring
// cross-wave at lag 5 phases of 16 steps. ND streamed per-lane contiguously:
// one aligned dwordx4 per 4 steps, 4 slots = 16-step lookahead; phase barrier
// is raw lgkmcnt(0)+s_barrier so prefetches stay in flight.
template<bool PRE>
__global__ __launch_bounds__(256, 1) void dp_kernel(
    const unsigned* __restrict__ ND2, const float* __restrict__ X,
    const float* __restrict__ Y, float* __restrict__ out)
{
  const int b   = blockIdx.x;
  const int tid = threadIdx.x;
  const int w   = tid >> 6;
  const int l   = tid & 63;

  __shared__ alignas(16) float ring_q[3][64];
  __shared__ alignas(16) int   ring_E[3][64];

  float P0q = 0.f, P1q = 0.f, dgq = (w == 0 && l == 0) ? 1.f : 0.f;
  int   P0E = EHUGE, P1E = EHUGE, dgE = (w == 0 && l == 0) ? 0 : EHUGE;
  float lastq = 0.f;
  int   lastE = EHUGE;

  const unsigned* nd2b = ND2 + (size_t)b * 132096;
  const long pbase = (long)(64 * w + l) * 516;
  const long off4l = 4L * (l >> 2);
  uint4 Q0, Q1, Q2, Q3;

  float xr0[16], xr1[16];
  float x20 = 0.f, x21 = 0.f;
  const float* ybase = Y + (size_t)b * 8192;

  if constexpr (PRE) {
    Q0 = *reinterpret_cast<const uint4*>(nd2b + (pbase + 0  - off4l));
    Q1 = *reinterpret_cast<const uint4*>(nd2b + (pbase + 4  - off4l));
    Q2 = *reinterpret_cast<const uint4*>(nd2b + (pbase + 8  - off4l));
    Q3 = *reinterpret_cast<const uint4*>(nd2b + (pbase + 12 - off4l));
  } else {
    const int a = 128 * w + 2 * l;
    const float4* px = (const float4*)(X + ((size_t)b * 512 + a) * 16);
    float4 u0 = px[0], u1 = px[1], u2 = px[2], u3 = px[3];
    float4 u4 = px[4], u5 = px[5], u6 = px[6], u7 = px[7];
    float ta[16] = { u0.x,u0.y,u0.z,u0.w, u1.x,u1.y,u1.z,u1.w,
                     u2.x,u2.y,u2.z,u2.w, u3.x,u3.y,u3.z,u3.w };
    float tb[16] = { u4.x,u4.y,u4.z,u4.w, u5.x,u5.y,u5.z,u5.w,
                     u6.x,u6.y,u6.z,u6.w, u7.x,u7.y,u7.z,u7.w };
    #pragma unroll
    for (int q = 0; q < 16; ++q) {
      xr0[q] = ta[q]; x20 = fmaf(ta[q], ta[q], x20);
      xr1[q] = tb[q]; x21 = fmaf(tb[q], tb[q], x21);
    }
  }

#define SDTW_CELLS(T, ND0, ND1, RQ, RE)                                        \
  {                                                                            \
    const int j_ = (T) - l;                                                    \
    const float f0_ = floorf(ND0), f1_ = floorf(ND1);                          \
    const float e0_ = __builtin_amdgcn_exp2f((ND0) - f0_);                     \
    const float e1_ = __builtin_amdgcn_exp2f((ND1) - f1_);                     \
    const int nI0_ = (int)f0_, nI1_ = (int)f1_;                                \
    const int sq_ = __builtin_amdgcn_update_dpp(                               \
        __builtin_bit_cast(int, P1q), __builtin_bit_cast(int, P1q),            \
        0x138, 0xF, 0xF, false);                                               \
    const int sE_ = __builtin_amdgcn_update_dpp(P1E, P1E, 0x138, 0xF, 0xF, false); \
    float upq_ = __builtin_bit_cast(float, sq_);                               \
    int   upE_ = sE_;                                                          \
    if (l == 0) { upq_ = (w == 0) ? 0.f : (RQ); upE_ = (w == 0) ? EHUGE : (RE); } \
    const int Em0_ = max(max(dgE, upE_), P0E);                                 \
    const float s0_ = ldexpf(dgq, dgE - Em0_) + ldexpf(upq_, upE_ - Em0_)      \
                    + ldexpf(P0q, P0E - Em0_);                                 \
    const float n0_ = e0_ * s0_;                                               \
    const int x0_ = (int)(__builtin_bit_cast(unsigned, n0_) >> 23) - 126;      \
    const float q0_ = ldexpf(n0_, -x0_);                                       \
    const int E0_ = Em0_ + x0_ + nI0_;                                         \
    const int Em1_ = max(max(P0E, P1E), E0_);                                  \
    const float s1_ = ldexpf(P0q, P0E - Em1_) + ldexpf(P1q, P1E - Em1_)        \
                    + ldexpf(q0_, E0_ - Em1_);                                 \
    const float n1_ = e1_ * s1_;                                               \
    const int x1_ = (int)(__builtin_bit_cast(unsigned, n1_) >> 23) - 126;      \
    const float q1_ = ldexpf(n1_, -x1_);                                       \
    const int E1_ = Em1_ + x1_ + nI1_;                                         \
    const bool v_ = (unsigned)(j_ - 1) < 512u;                                 \
    dgq = upq_; dgE = upE_;                                                    \
    P0q = v_ ? q0_ : 0.f;  P0E = v_ ? E0_ : EHUGE;                             \
    P1q = v_ ? q1_ : 0.f;  P1E = v_ ? E1_ : EHUGE;                             \
    lastq = v_ ? q1_ : lastq;  lastE = v_ ? E1_ : lastE;                       \
    if (l == 63 && w < 3 && v_) {                                              \
      ring_q[w][(j_ - 1) & 63] = P1q;  ring_E[w][(j_ - 1) & 63] = P1E;         \
    }                                                                          \
  }

#define SDTW_PSTEP(T, DW, RQ, RE)                                              \
  {                                                                            \
    const unsigned dw_ = (DW);                                                 \
    const float nd0_ = (float)__builtin_bit_cast(_Float16, (unsigned short)(dw_ & 0xffffu)); \
    const float nd1_ = (float)__builtin_bit_cast(_Float16, (unsigned short)(dw_ >> 16));     \
    SDTW_CELLS(T, nd0_, nd1_, RQ, RE)                                          \
  }

#define SDTW_GROUP(QS, T1, RQ0,RE0, RQ1,RE1, RQ2,RE2, RQ3,RE3)                 \
  {                                                                            \
    const uint4 qv_ = QS;                                                      \
    QS = *reinterpret_cast<const uint4*>(nd2b + (pbase + ((T1) + 15) - off4l));\
    SDTW_PSTEP((T1) + 0, qv_.x, RQ0, RE0)                                      \
    SDTW_PSTEP((T1) + 1, qv_.y, RQ1, RE1)                                      \
    SDTW_PSTEP((T1) + 2, qv_.z, RQ2, RE2)                                      \
    SDTW_PSTEP((T1) + 3, qv_.w, RQ3, RE3)                                      \
  }

#define SDTW_NSTEP(T, RQ, RE)                                                  \
  {                                                                            \
    int jc_ = (T) - l - 1; jc_ = jc_ < 0 ? 0 : (jc_ > 511 ? 511 : jc_);        \
    const float4* py_ = (const float4*)(ybase + (size_t)jc_ * 16);             \
    float4 v0_ = py_[0], v1_ = py_[1], v2_ = py_[2], v3_ = py_[3];             \
    float yv_[16] = { v0_.x,v0_.y,v0_.z,v0_.w, v1_.x,v1_.y,v1_.z,v1_.w,        \
                      v2_.x,v2_.y,v2_.z,v2_.w, v3_.x,v3_.y,v3_.z,v3_.w };      \
    float y2_ = 0.f, d0_ = 0.f, d1_ = 0.f;                                     \
    _Pragma("unroll")                                                          \
    for (int q = 0; q < 16; ++q) {                                             \
      y2_ = fmaf(yv_[q], yv_[q], y2_);                                         \
      d0_ = fmaf(xr0[q], yv_[q], d0_);                                         \
      d1_ = fmaf(xr1[q], yv_[q], d1_);                                         \
    }                                                                          \
    const float nd0_ = (2.f * d0_ - x20 - y2_) * INV_LN2;                      \
    const float nd1_ = (2.f * d1_ - x21 - y2_) * INV_LN2;                      \
    SDTW_CELLS(T, nd0_, nd1_, RQ, RE)                                          \
  }

  for (int ph = 0; ph < 51; ++ph) {
    const int pw = ph - 5 * w;
    if (pw >= 0 && pw < 36) {
      const int tb = 16 * pw + 1;
      const int wi = (w > 0) ? w - 1 : 0;
      const int rb = 4 * (pw & 3);
      const float4* rpq = reinterpret_cast<const float4*>(&ring_q[wi][0]);
      const int4*   rpe = reinterpret_cast<const int4*>(&ring_E[wi][0]);
      const float4 gq0 = rpq[rb], gq1 = rpq[rb+1], gq2 = rpq[rb+2], gq3 = rpq[rb+3];
      const int4   ge0 = rpe[rb], ge1 = rpe[rb+1], ge2 = rpe[rb+2], ge3 = rpe[rb+3];
      if constexpr (PRE) {
        SDTW_GROUP(Q0, tb,      gq0.x, ge0.x, gq0.y, ge0.y, gq0.z, ge0.z, gq0.w, ge0.w)
        SDTW_GROUP(Q1, tb + 4,  gq1.x, ge1.x, gq1.y, ge1.y, gq1.z, ge1.z, gq1.w, ge1.w)
        SDTW_GROUP(Q2, tb + 8,  gq2.x, ge2.x, gq2.y, ge2.y, gq2.z, ge2.z, gq2.w, ge2.w)
        SDTW_GROUP(Q3, tb + 12, gq3.x, ge3.x, gq3.y, ge3.y, gq3.z, ge3.z, gq3.w, ge3.w)
      } else {
        SDTW_NSTEP(tb + 0,  gq0.x, ge0.x) SDTW_NSTEP(tb + 1,  gq0.y, ge0.y)
        SDTW_NSTEP(tb + 2,  gq0.z, ge0.z) SDTW_NSTEP(tb + 3,  gq0.w, ge0.w)
        SDTW_NSTEP(tb + 4,  gq1.x, ge1.x) SDTW_NSTEP(tb + 5,  gq1.y, ge1.y)
        SDTW_NSTEP(tb + 6,  gq1.z, ge1.z) SDTW_NSTEP(tb + 7,  gq1.w, ge1.w)
        SDTW_NSTEP(tb + 8,  gq2.x, ge2.x) SDTW_NSTEP(tb + 9,  gq2.y, ge2.y)
        SDTW_NSTEP(tb + 10, gq2.z, ge2.z) SDTW_NSTEP(tb + 11, gq2.w, ge2.w)
        SDTW_NSTEP(tb + 12, gq3.x, ge3.x) SDTW_NSTEP(tb + 13, gq3.y, ge3.y)
        SDTW_NSTEP(tb + 14, gq3.z, ge3.z) SDTW_NSTEP(tb + 15, gq3.w, ge3.w)
      }
    }
    // LDS-only barrier: drain lgkm (ring ds ops), keep global prefetches in flight
    __builtin_amdgcn_sched_barrier(0);
    asm volatile("s_waitcnt lgkmcnt(0)" ::: "memory");
    __builtin_amdgcn_s_barrier();
    __builtin_amdgcn_sched_barrier(0);
  }
#undef SDTW_CELLS
#undef SDTW_PSTEP
#undef SDTW_GROUP
#undef SDTW_NSTEP

  // V(512,512) = lastq * 2^lastE ; r = -ln2 * (log2(q) + E)
  if (tid == 255)
    out[b] = -LN2f * (__builtin_amdgcn_logf(lastq) + (float)lastE);
}

extern "C" void kernel_launch(void* const* d_in, const int* in_sizes, int n_in,
                              void* d_out, int out_size, void* d_ws, size_t ws_size,
                              hipStream_t stream)
{
  const float* x = (const float*)d_in[0];
  const float* y = (const float*)d_in[1];
  float* o = (float*)d_out;
  // layout: 64-dword front guard | 64 batches x 132096 dwords | 128-dword tail guard
  const size_t need = (size_t)(64 + (size_t)64 * 132096 + 128) * 4;
  unsigned* nd2 = (unsigned*)d_ws + 64;
  if (ws_size >= need) {
    dist2_kernel<<<dim3(64, 64), 256, 0, stream>>>(x, y, nd2);
    dp_kernel<true><<<64, 256, 0, stream>>>(nd2, x, y, o);
  } else {
    dp_kernel<false><<<64, 256, 0, stream>>>(nullptr, x, y, o);
  }
}

// Round 10
// 143.685 us; speedup vs baseline: 1.0969x; 1.0056x over previous
//
#include <hip/hip_runtime.h>

#define BIGV 1e10f
constexpr float INV_LN2 = 1.4426950408889634f;
constexpr float LN2f    = 0.6931471805599453f;

// ---------------- Phase 1: ND[b][r][e] f16, stride 516 elems ----------------
// Row r holds nd(r, jy) = -|x_r - y_jy|^2/ln2 at elem e = jy + (r&3); elems
// outside [r&3, 511+(r&3)] get -60000 guards. The (r&3) shift makes the DP
// lane's 4-step uint2 loads 8B-aligned (stride 516*2B = 1032 ≡ 0 mod 8).
__global__ __launch_bounds__(256) void dist_kernel(
    const float* __restrict__ X, const float* __restrict__ Y,
    unsigned short* __restrict__ ND)
{
  const int b  = blockIdx.x;
  const int gy = blockIdx.y;
  const int t  = threadIdx.x;

  __shared__ float4 ysh4[512][4];   // quad index XOR-swizzled by (j>>6)&3
  __shared__ float  y2sh[512];
  __shared__ float4 xsh4[32][4];

  const float4* yb4 = (const float4*)(Y + (size_t)b * 8192);
  const float4* xb4 = (const float4*)(X + (size_t)b * 8192 + (size_t)(32 * gy) * 16);

  for (int i = t; i < 2048; i += 256) {
    const int j = i >> 2, q = i & 3;
    ysh4[j][q ^ ((j >> 6) & 3)] = yb4[i];
  }
  if (t < 128) xsh4[t >> 2][t & 3] = xb4[t];
  __syncthreads();
  for (int rr = t; rr < 512; rr += 256) {
    float4 a = ysh4[rr][0], bb = ysh4[rr][1], cc = ysh4[rr][2], dd = ysh4[rr][3];
    float s = 0.f;
    s = fmaf(a.x,a.x,s);  s = fmaf(a.y,a.y,s);  s = fmaf(a.z,a.z,s);  s = fmaf(a.w,a.w,s);
    s = fmaf(bb.x,bb.x,s); s = fmaf(bb.y,bb.y,s); s = fmaf(bb.z,bb.z,s); s = fmaf(bb.w,bb.w,s);
    s = fmaf(cc.x,cc.x,s); s = fmaf(cc.y,cc.y,s); s = fmaf(cc.z,cc.z,s); s = fmaf(cc.w,cc.w,s);
    s = fmaf(dd.x,dd.x,s); s = fmaf(dd.y,dd.y,s); s = fmaf(dd.z,dd.z,s); s = fmaf(dd.w,dd.w,s);
    y2sh[rr] = s;
  }
  __syncthreads();

  const int rl = t >> 3, sidx = t & 7;
  const int r  = 32 * gy + rl;
  const int sh = r & 3;
  const float4 xq0 = xsh4[rl][0], xq1 = xsh4[rl][1], xq2 = xsh4[rl][2], xq3 = xsh4[rl][3];
  float x2 = 0.f;
  x2 = fmaf(xq0.x,xq0.x,x2); x2 = fmaf(xq0.y,xq0.y,x2); x2 = fmaf(xq0.z,xq0.z,x2); x2 = fmaf(xq0.w,xq0.w,x2);
  x2 = fmaf(xq1.x,xq1.x,x2); x2 = fmaf(xq1.y,xq1.y,x2); x2 = fmaf(xq1.z,xq1.z,x2); x2 = fmaf(xq1.w,xq1.w,x2);
  x2 = fmaf(xq2.x,xq2.x,x2); x2 = fmaf(xq2.y,xq2.y,x2); x2 = fmaf(xq2.z,xq2.z,x2); x2 = fmaf(xq2.w,xq2.w,x2);
  x2 = fmaf(xq3.x,xq3.x,x2); x2 = fmaf(xq3.y,xq3.y,x2); x2 = fmaf(xq3.z,xq3.z,x2); x2 = fmaf(xq3.w,xq3.w,x2);

  unsigned short* rowp = ND + ((size_t)b * 512 + (size_t)r) * 516;

  auto do_group = [&](int e0) {
    unsigned h0 = 0, h1 = 0;
    #pragma unroll
    for (int k = 0; k < 4; ++k) {
      const int e  = e0 + k;
      const int jy = e - sh;
      const int jc = min(max(jy, 0), 511);
      const int xr = (jc >> 6) & 3;
      const float4 y0 = ysh4[jc][0 ^ xr], y1 = ysh4[jc][1 ^ xr],
                   y2v = ysh4[jc][2 ^ xr], y3 = ysh4[jc][3 ^ xr];
      float dt = 0.f;
      dt = fmaf(xq0.x,y0.x,dt); dt = fmaf(xq0.y,y0.y,dt); dt = fmaf(xq0.z,y0.z,dt); dt = fmaf(xq0.w,y0.w,dt);
      dt = fmaf(xq1.x,y1.x,dt); dt = fmaf(xq1.y,y1.y,dt); dt = fmaf(xq1.z,y1.z,dt); dt = fmaf(xq1.w,y1.w,dt);
      dt = fmaf(xq2.x,y2v.x,dt); dt = fmaf(xq2.y,y2v.y,dt); dt = fmaf(xq2.z,y2v.z,dt); dt = fmaf(xq2.w,y2v.w,dt);
      dt = fmaf(xq3.x,y3.x,dt); dt = fmaf(xq3.y,y3.y,dt); dt = fmaf(xq3.z,y3.z,dt); dt = fmaf(xq3.w,y3.w,dt);
      const float nd = ((unsigned)jy < 512u)
                         ? (2.f * dt - x2 - y2sh[jc]) * INV_LN2 : -60000.f;
      const unsigned hv = (unsigned)__builtin_bit_cast(unsigned short, (_Float16)nd);
      if (k == 0) h0 = hv;        else if (k == 1) h0 |= hv << 16;
      else if (k == 2) h1 = hv;   else h1 |= hv << 16;
    }
    uint2 v; v.x = h0; v.y = h1;
    *(uint2*)(rowp + e0) = v;
  };

  for (int u = 0; u < 16; ++u) do_group(64 * sidx + 4 * u);
  if (sidx == 7) do_group(512);
}

// ---------------- Phase 2: log2-domain wavefront DP, 8-wave pipeline ----------------
// Wave w owns DP rows 64w+1..64w+64; lane l owns row r+1 (r = 64w+l).
// Step t: lane l at col j = t-l. Cross-lane: DPP wf_sr1 of P (dg = prev up).
// Cross-wave: ring[w][64] in LDS, lag 5 phases of K=16 (same proof as r5-r9).
// 2 waves/SIMD fill dependency stalls. nd streamed as aligned uint2 / 4 steps.
template<bool PRE>
__global__ __launch_bounds__(512, 1) void dp_kernel(
    const unsigned short* __restrict__ ND, const float* __restrict__ X,
    const float* __restrict__ Y, float* __restrict__ out)
{
  const int b   = blockIdx.x;
  const int tid = threadIdx.x;
  const int w   = tid >> 6;
  const int l   = tid & 63;
  const int r   = 64 * w + l;

  __shared__ alignas(16) float ring[8][64];   // rows 0..6 = boundaries, 7 = dump

  float P  = BIGV;
  float dg = (w == 0 && l == 0) ? 0.f : BIGV;
  const bool doring = (l == 63) && (w < 7);
  const int  lq = l >> 2;

  const uint2* rp = nullptr;
  uint2 cur0, cur1, cur2, cur3, nxt0, nxt1, nxt2, nxt3;
  float xr0[16];
  float x2 = 0.f;
  const float4* yb4 = (const float4*)(Y + (size_t)b * 8192);

  if constexpr (PRE) {
    rp = (const uint2*)(ND + ((size_t)b * 512 + (size_t)r) * 516);
    cur0 = rp[min(max(0 - lq, 0), 128)];
    cur1 = rp[min(max(1 - lq, 0), 128)];
    cur2 = rp[min(max(2 - lq, 0), 128)];
    cur3 = rp[min(max(3 - lq, 0), 128)];
  } else {
    const float4* px = (const float4*)(X + ((size_t)b * 512 + r) * 16);
    float4 u0 = px[0], u1 = px[1], u2 = px[2], u3 = px[3];
    float tv[16] = { u0.x,u0.y,u0.z,u0.w, u1.x,u1.y,u1.z,u1.w,
                     u2.x,u2.y,u2.z,u2.w, u3.x,u3.y,u3.z,u3.w };
    #pragma unroll
    for (int q = 0; q < 16; ++q) { xr0[q] = tv[q]; x2 = fmaf(tv[q], tv[q], x2); }
  }

#define DPSTEP(K, DW, HI, RV, GUARDED)                                         \
  {                                                                            \
    float nd_;                                                                 \
    if constexpr (PRE) {                                                       \
      nd_ = (float)__builtin_bit_cast(_Float16,                                \
              (unsigned short)((HI) ? ((DW) >> 16) : ((DW) & 0xffffu)));       \
    } else {                                                                   \
      const int jy_ = tml + (K);                                               \
      const int jc_ = min(max(jy_, 0), 511);                                   \
      float4 q0 = yb4[4*jc_+0], q1 = yb4[4*jc_+1],                             \
             q2 = yb4[4*jc_+2], q3 = yb4[4*jc_+3];                             \
      float yv_[16] = { q0.x,q0.y,q0.z,q0.w, q1.x,q1.y,q1.z,q1.w,              \
                        q2.x,q2.y,q2.z,q2.w, q3.x,q3.y,q3.z,q3.w };            \
      float y2_ = 0.f, d0_ = 0.f;                                              \
      _Pragma("unroll")                                                        \
      for (int q = 0; q < 16; ++q) {                                           \
        y2_ = fmaf(yv_[q], yv_[q], y2_);                                       \
        d0_ = fmaf(xr0[q], yv_[q], d0_);                                       \
      }                                                                        \
      nd_ = (2.f * d0_ - x2 - y2_) * INV_LN2;                                  \
    }                                                                          \
    const int sp_ = __builtin_amdgcn_update_dpp(__builtin_bit_cast(int, P),    \
        __builtin_bit_cast(int, P), 0x138, 0xF, 0xF, false);                   \
    float up_ = __builtin_bit_cast(float, sp_);                                \
    if (l == 0) up_ = (w == 0) ? BIGV : (RV);                                  \
    const float mn_ = fminf(fminf(dg, up_), P);                                \
    const float s_  = __builtin_amdgcn_exp2f(mn_ - dg)                         \
                    + __builtin_amdgcn_exp2f(mn_ - up_)                        \
                    + __builtin_amdgcn_exp2f(mn_ - P);                         \
    float c_ = mn_ - __builtin_amdgcn_logf(s_) - nd_;                          \
    if (GUARDED) c_ = ((unsigned)(tml + (K)) < 512u) ? c_ : BIGV;              \
    dg = up_; P = c_;                                                          \
    if (doring) ring[w][(tb64 + (K)) & 63] = c_;                               \
  }

#define DP16(G)                                                                \
    DPSTEP(0,  cur0.x, 0, rg0.x, G) DPSTEP(1,  cur0.x, 1, rg0.y, G)            \
    DPSTEP(2,  cur0.y, 0, rg0.z, G) DPSTEP(3,  cur0.y, 1, rg0.w, G)            \
    DPSTEP(4,  cur1.x, 0, rg1.x, G) DPSTEP(5,  cur1.x, 1, rg1.y, G)            \
    DPSTEP(6,  cur1.y, 0, rg1.z, G) DPSTEP(7,  cur1.y, 1, rg1.w, G)            \
    DPSTEP(8,  cur2.x, 0, rg2.x, G) DPSTEP(9,  cur2.x, 1, rg2.y, G)            \
    DPSTEP(10, cur2.y, 0, rg2.z, G) DPSTEP(11, cur2.y, 1, rg2.w, G)            \
    DPSTEP(12, cur3.x, 0, rg3.x, G) DPSTEP(13, cur3.x, 1, rg3.y, G)            \
    DPSTEP(14, cur3.y, 0, rg3.z, G) DPSTEP(15, cur3.y, 1, rg3.w, G)

  for (int p = 0; p < 70; ++p) {
    const int pw = p - 5 * w;
    if ((unsigned)pw < 36u) {
      const int tb   = 16 * pw + 1;
      const int tml  = tb - l - 1;
      const int tb64 = tb - 64;
      const int wi   = (w > 0) ? (w - 1) : 0;
      const float4* rpq = (const float4*)(&ring[wi][0]);
      const int rb = 4 * (pw & 3);
      const float4 rg0 = rpq[rb], rg1 = rpq[rb+1], rg2 = rpq[rb+2], rg3 = rpq[rb+3];
      if constexpr (PRE) {
        const int gb = 4 * pw + 4;
        nxt0 = rp[min(max(gb + 0 - lq, 0), 128)];
        nxt1 = rp[min(max(gb + 1 - lq, 0), 128)];
        nxt2 = rp[min(max(gb + 2 - lq, 0), 128)];
        nxt3 = rp[min(max(gb + 3 - lq, 0), 128)];
      }
      if ((unsigned)(pw - 4) < 28u) {
        DP16(false)
      } else {
        DP16(true)
      }
      if constexpr (PRE) { cur0 = nxt0; cur1 = nxt1; cur2 = nxt2; cur3 = nxt3; }
    }
    __builtin_amdgcn_sched_barrier(0);
    asm volatile("s_waitcnt lgkmcnt(0)" ::: "memory");
    __builtin_amdgcn_s_barrier();
    __builtin_amdgcn_sched_barrier(0);
  }

  // peel: wave 7's pw = 35 (tb = 561), steps t = 561..575 only (skip t = 576)
  if (w == 7) {
    const int tb   = 561;
    const int tml  = tb - l - 1;
    const int tb64 = tb - 64;
    const float4* rpq = (const float4*)(&ring[6][0]);
    const int rb = 4 * (35 & 3);
    const float4 rg0 = rpq[rb], rg1 = rpq[rb+1], rg2 = rpq[rb+2], rg3 = rpq[rb+3];
    DPSTEP(0,  cur0.x, 0, rg0.x, true) DPSTEP(1,  cur0.x, 1, rg0.y, true)
    DPSTEP(2,  cur0.y, 0, rg0.z, true) DPSTEP(3,  cur0.y, 1, rg0.w, true)
    DPSTEP(4,  cur1.x, 0, rg1.x, true) DPSTEP(5,  cur1.x, 1, rg1.y, true)
    DPSTEP(6,  cur1.y, 0, rg1.z, true) DPSTEP(7,  cur1.y, 1, rg1.w, true)
    DPSTEP(8,  cur2.x, 0, rg2.x, true) DPSTEP(9,  cur2.x, 1, rg2.y, true)
    DPSTEP(10, cur2.y, 0, rg2.z, true) DPSTEP(11, cur2.y, 1, rg2.w, true)
    DPSTEP(12, cur3.x, 0, rg3.x, true) DPSTEP(13, cur3.x, 1, rg3.y, true)
    DPSTEP(14, cur3.y, 0, rg3.z, true)
  }
#undef DP16
#undef DPSTEP

  if (tid == 511) out[b] = P * LN2f;   // P = r'(512,512) in log2 units
}

extern "C" void kernel_launch(void* const* d_in, const int* in_sizes, int n_in,
                              void* d_out, int out_size, void* d_ws, size_t ws_size,
                              hipStream_t stream)
{
  const float* x = (const float*)d_in[0];
  const float* y = (const float*)d_in[1];
  float* o = (float*)d_out;
  const size_t need = (size_t)64 * 512 * 516 * 2;   // 33,816,576 B
  if (ws_size >= need) {
    unsigned short* nd = (unsigned short*)d_ws;
    dist_kernel<<<dim3(64, 16), 256, 0, stream>>>(x, y, nd);
    dp_kernel<true><<<64, 512, 0, stream>>>(nd, x, y, o);
  } else {
    dp_kernel<false><<<64, 512, 0, stream>>>(nullptr, x, y, o);
  }
}